// Round 1
// baseline (850.902 us; speedup 1.0000x reference)
//
#include <hip/hip_runtime.h>

// Max-unpooling scatter-add.
// updates: [B=16, H=128, W=128, C=64] fp32
// argmax:  same shape, int32, flattened TF index ((y*OW + x)*C + c_ignored)
// out:     [B, OH=256, OW=256, C] fp32, zero-init then out[b,y,x,c] += updates
//
// OW*C = 16384 = 2^14, C = 64 = 2^6, OH = OW = 256 -> decode is bit ops:
//   y = (a >> 14) & 255; x = (a >> 6) & 255
//   dest = (b << 22) | (y << 14) | (x << 6) | c

#define B_  16
#define H_  128
#define W_  128
#define C_  64
#define OH_ 256
#define OW_ 256

__global__ void zero_out_kernel(float4* __restrict__ out, int n4) {
    int stride = gridDim.x * blockDim.x;
    for (int i = blockIdx.x * blockDim.x + threadIdx.x; i < n4; i += stride) {
        out[i] = make_float4(0.f, 0.f, 0.f, 0.f);
    }
}

__global__ void unpool_scatter_kernel(const float4* __restrict__ upd4,
                                      const int4* __restrict__ amx4,
                                      float* __restrict__ out,
                                      int n4) {
    int i = blockIdx.x * blockDim.x + threadIdx.x;
    if (i >= n4) return;

    float4 u = upd4[i];
    int4   a = amx4[i];

    // flat element index of first of the 4 elements this thread handles
    int e = i << 2;                 // [0, B*H*W*C)
    int c = e & (C_ - 1);           // channel of element 0 (c+1..c+3 follow)
    int b = e >> 20;                // e / (H*W*C) = e / 2^20
    int base_b = b << 22;           // b * OH*OW*C

    {
        int y = (a.x >> 14) & (OH_ - 1);
        int x = (a.x >> 6)  & (OW_ - 1);
        atomicAdd(&out[base_b + (y << 14) + (x << 6) + c], u.x);
    }
    {
        int y = (a.y >> 14) & (OH_ - 1);
        int x = (a.y >> 6)  & (OW_ - 1);
        atomicAdd(&out[base_b + (y << 14) + (x << 6) + c + 1], u.y);
    }
    {
        int y = (a.z >> 14) & (OH_ - 1);
        int x = (a.z >> 6)  & (OW_ - 1);
        atomicAdd(&out[base_b + (y << 14) + (x << 6) + c + 2], u.z);
    }
    {
        int y = (a.w >> 14) & (OH_ - 1);
        int x = (a.w >> 6)  & (OW_ - 1);
        atomicAdd(&out[base_b + (y << 14) + (x << 6) + c + 3], u.w);
    }
}

extern "C" void kernel_launch(void* const* d_in, const int* in_sizes, int n_in,
                              void* d_out, int out_size, void* d_ws, size_t ws_size,
                              hipStream_t stream) {
    const float* updates = (const float*)d_in[0];
    const int*   argmax  = (const int*)d_in[1];
    float*       out     = (float*)d_out;

    int n_in_elems  = in_sizes[0];          // 16*128*128*64 = 16,777,216
    int n_out_elems = out_size;             // 16*256*256*64 = 67,108,864

    // Pass 1: zero the output (grid-stride float4 stores).
    int n_out4 = n_out_elems >> 2;
    zero_out_kernel<<<2048, 256, 0, stream>>>((float4*)d_out, n_out4);

    // Pass 2: scatter-add, 4 contiguous channel elements per thread.
    int n4 = n_in_elems >> 2;               // 4,194,304 threads
    int block = 256;
    int grid = (n4 + block - 1) / block;    // 16384 blocks
    unpool_scatter_kernel<<<grid, block, 0, stream>>>(
        (const float4*)updates, (const int4*)argmax, out, n4);
}

// Round 2
// 335.323 us; speedup vs baseline: 2.5376x; 2.5376x over previous
//
#include <hip/hip_runtime.h>

// Max-unpooling scatter-add, atomic-free counting-sort design.
// updates: [B=16, H=128, W=128, C=64] fp32
// argmax:  same shape, int32, TF flat index ((y*OW + x)*C + c_ignored)
// out:     [B, OH=256, OW=256, C] fp32
//
// out_idx = (b<<22)|(y<<14)|(x<<6)|c  with y=(a>>14)&255, x=(a>>6)&255,
// b,c from position. bin = out_idx>>13 = (b<<9)|(y<<1)|(x>>7)  (8192 bins,
// 32 KiB of output each). li = out_idx & 8191 = ((x&127)<<6)|c.

#define B_       16
#define C_       64
#define N_ELEM   (16 * 128 * 128 * 64)   // 16,777,216
#define N4       (N_ELEM / 4)            // 4,194,304
#define NBINS    8192
#define BIN_ELEMS 8192                   // floats per bin region (32 KiB)
#define NB       256                     // binning blocks
#define BT       1024                    // threads for K1/K3
#define PER_BLOCK4 (N4 / NB)             // 16384 int4 per block
#define PER_THREAD4 (PER_BLOCK4 / BT)    // 16

// ---------------- K1: per-block histogram ----------------
__global__ __launch_bounds__(BT) void count_kernel(const int4* __restrict__ amx4,
                                                   int* __restrict__ hist) {
    __shared__ int h[NBINS];
    for (int j = threadIdx.x; j < NBINS; j += BT) h[j] = 0;
    __syncthreads();
    int base4 = blockIdx.x * PER_BLOCK4;
    #pragma unroll 4
    for (int t = 0; t < PER_THREAD4; ++t) {
        int i = base4 + t * BT + threadIdx.x;   // coalesced int4
        int4 a = amx4[i];
        int e = i << 2;
        int bhi = (e >> 20) << 9;
        int y, x;
        y = (a.x >> 14) & 255; x = (a.x >> 6) & 255; atomicAdd(&h[bhi | (y << 1) | (x >> 7)], 1);
        y = (a.y >> 14) & 255; x = (a.y >> 6) & 255; atomicAdd(&h[bhi | (y << 1) | (x >> 7)], 1);
        y = (a.z >> 14) & 255; x = (a.z >> 6) & 255; atomicAdd(&h[bhi | (y << 1) | (x >> 7)], 1);
        y = (a.w >> 14) & 255; x = (a.w >> 6) & 255; atomicAdd(&h[bhi | (y << 1) | (x >> 7)], 1);
    }
    __syncthreads();
    int* hrow = hist + (size_t)blockIdx.x * NBINS;
    for (int j = threadIdx.x; j < NBINS; j += BT) hrow[j] = h[j];
}

// ---------------- K2a: column scan: hist -> per-block prefix P (in place), totals T ----------------
__global__ __launch_bounds__(256) void colscan_kernel(int* __restrict__ hist,
                                                      int* __restrict__ T) {
    int bin = blockIdx.x * 256 + threadIdx.x;   // grid = NBINS/256
    int run = 0;
    for (int blk = 0; blk < NB; ++blk) {
        int idx = blk * NBINS + bin;
        int v = hist[idx];
        hist[idx] = run;     // exclusive prefix over blocks
        run += v;
    }
    T[bin] = run;
}

// ---------------- K2b: exclusive scan of T[NBINS] -> G ----------------
__global__ __launch_bounds__(256) void scan_kernel(const int* __restrict__ T,
                                                   int* __restrict__ G) {
    __shared__ int part[256];
    const int PER = NBINS / 256;   // 32
    int t = threadIdx.x;
    int loc[PER];
    int s = 0;
    #pragma unroll
    for (int j = 0; j < PER; ++j) { loc[j] = s; s += T[t * PER + j]; }
    part[t] = s;
    __syncthreads();
    for (int off = 1; off < 256; off <<= 1) {
        int v = (t >= off) ? part[t - off] : 0;
        __syncthreads();
        part[t] += v;
        __syncthreads();
    }
    int pre = (t == 0) ? 0 : part[t - 1];
    #pragma unroll
    for (int j = 0; j < PER; ++j) G[t * PER + j] = pre + loc[j];
}

// ---------------- K3: place (li, val) pairs at exact offsets ----------------
__global__ __launch_bounds__(BT) void scatter_kernel(const float4* __restrict__ upd4,
                                                     const int4* __restrict__ amx4,
                                                     const int* __restrict__ P,
                                                     const int* __restrict__ G,
                                                     int2* __restrict__ pairs) {
    __shared__ int cur[NBINS];
    const int* Prow = P + (size_t)blockIdx.x * NBINS;
    for (int j = threadIdx.x; j < NBINS; j += BT) cur[j] = G[j] + Prow[j];
    __syncthreads();
    int base4 = blockIdx.x * PER_BLOCK4;
    for (int t = 0; t < PER_THREAD4; ++t) {
        int i = base4 + t * BT + threadIdx.x;
        int4   a = amx4[i];
        float4 u = upd4[i];
        int e = i << 2;
        int c = e & (C_ - 1);
        int bhi = (e >> 20) << 9;
        int y, x, bin, pos;
        y = (a.x >> 14) & 255; x = (a.x >> 6) & 255;
        bin = bhi | (y << 1) | (x >> 7);
        pos = atomicAdd(&cur[bin], 1);
        pairs[pos] = make_int2(((x & 127) << 6) | c, __float_as_int(u.x));

        y = (a.y >> 14) & 255; x = (a.y >> 6) & 255;
        bin = bhi | (y << 1) | (x >> 7);
        pos = atomicAdd(&cur[bin], 1);
        pairs[pos] = make_int2(((x & 127) << 6) | (c + 1), __float_as_int(u.y));

        y = (a.z >> 14) & 255; x = (a.z >> 6) & 255;
        bin = bhi | (y << 1) | (x >> 7);
        pos = atomicAdd(&cur[bin], 1);
        pairs[pos] = make_int2(((x & 127) << 6) | (c + 2), __float_as_int(u.z));

        y = (a.w >> 14) & 255; x = (a.w >> 6) & 255;
        bin = bhi | (y << 1) | (x >> 7);
        pos = atomicAdd(&cur[bin], 1);
        pairs[pos] = make_int2(((x & 127) << 6) | (c + 3), __float_as_int(u.w));
    }
}

// ---------------- K4: per-bin LDS accumulate + coalesced store ----------------
__global__ __launch_bounds__(512) void accum_kernel(const int2* __restrict__ pairs,
                                                    const int* __restrict__ T,
                                                    const int* __restrict__ G,
                                                    float4* __restrict__ out4) {
    __shared__ float acc[BIN_ELEMS];
    int bin = blockIdx.x;
    for (int j = threadIdx.x; j < BIN_ELEMS; j += 512) acc[j] = 0.f;
    __syncthreads();
    int n = T[bin], off = G[bin];
    for (int j = threadIdx.x; j < n; j += 512) {
        int2 p = pairs[off + j];
        atomicAdd(&acc[p.x], __int_as_float(p.y));
    }
    __syncthreads();
    float4* dst = out4 + (size_t)bin * (BIN_ELEMS / 4);
    for (int j = threadIdx.x; j < BIN_ELEMS / 4; j += 512) {
        dst[j] = make_float4(acc[4 * j], acc[4 * j + 1], acc[4 * j + 2], acc[4 * j + 3]);
    }
}

// ---------------- Fallback (round-1 atomic path) ----------------
__global__ void zero_out_kernel(float4* __restrict__ out, int n4) {
    int stride = gridDim.x * blockDim.x;
    for (int i = blockIdx.x * blockDim.x + threadIdx.x; i < n4; i += stride)
        out[i] = make_float4(0.f, 0.f, 0.f, 0.f);
}

__global__ void unpool_atomic_kernel(const float4* __restrict__ upd4,
                                     const int4* __restrict__ amx4,
                                     float* __restrict__ out, int n4) {
    int i = blockIdx.x * blockDim.x + threadIdx.x;
    if (i >= n4) return;
    float4 u = upd4[i];
    int4   a = amx4[i];
    int e = i << 2;
    int c = e & (C_ - 1);
    int base_b = (e >> 20) << 22;
    int y, x;
    y = (a.x >> 14) & 255; x = (a.x >> 6) & 255;
    atomicAdd(&out[base_b + (y << 14) + (x << 6) + c], u.x);
    y = (a.y >> 14) & 255; x = (a.y >> 6) & 255;
    atomicAdd(&out[base_b + (y << 14) + (x << 6) + c + 1], u.y);
    y = (a.z >> 14) & 255; x = (a.z >> 6) & 255;
    atomicAdd(&out[base_b + (y << 14) + (x << 6) + c + 2], u.z);
    y = (a.w >> 14) & 255; x = (a.w >> 6) & 255;
    atomicAdd(&out[base_b + (y << 14) + (x << 6) + c + 3], u.w);
}

extern "C" void kernel_launch(void* const* d_in, const int* in_sizes, int n_in,
                              void* d_out, int out_size, void* d_ws, size_t ws_size,
                              hipStream_t stream) {
    const float* updates = (const float*)d_in[0];
    const int*   argmax  = (const int*)d_in[1];

    size_t pairs_bytes = (size_t)N_ELEM * 8;
    size_t hist_bytes  = (size_t)NB * NBINS * 4;
    size_t need = pairs_bytes + hist_bytes + 2 * (size_t)NBINS * 4;

    if (in_sizes[0] == N_ELEM && ws_size >= need) {
        char* ws = (char*)d_ws;
        int2* pairs = (int2*)ws;
        int*  hist  = (int*)(ws + pairs_bytes);
        int*  T     = (int*)(ws + pairs_bytes + hist_bytes);
        int*  G     = T + NBINS;

        count_kernel  <<<NB, BT, 0, stream>>>((const int4*)argmax, hist);
        colscan_kernel<<<NBINS / 256, 256, 0, stream>>>(hist, T);
        scan_kernel   <<<1, 256, 0, stream>>>(T, G);
        scatter_kernel<<<NB, BT, 0, stream>>>((const float4*)updates,
                                              (const int4*)argmax, hist, G, pairs);
        accum_kernel  <<<NBINS, 512, 0, stream>>>(pairs, T, G, (float4*)d_out);
    } else {
        int n_out4 = out_size >> 2;
        zero_out_kernel<<<2048, 256, 0, stream>>>((float4*)d_out, n_out4);
        int n4 = in_sizes[0] >> 2;
        unpool_atomic_kernel<<<(n4 + 255) / 256, 256, 0, stream>>>(
            (const float4*)updates, (const int4*)argmax, (float*)d_out, n4);
    }
}

// Round 3
// 228.772 us; speedup vs baseline: 3.7194x; 1.4658x over previous
//
#include <hip/hip_runtime.h>

// Max-unpooling scatter-add, atomic-free counting-sort, round 3:
// in-LDS per-chunk sort in the scatter pass so pair writes are bin-contiguous.
//
// out_idx = (b<<22)|(y<<14)|(x<<6)|c,  y=(a>>14)&255, x=(a>>6)&255.
// global bin g = out_idx>>13 = (b<<9)|ybx, ybx=(y<<1)|(x>>7)  (8192 bins,
// 32 KiB output each).  local index li = ((x&127)<<6)|c  (13 bits).
// Each binning block covers one b => only 512 local bins.

#define C_        64
#define N_ELEM    (16 * 128 * 128 * 64)   // 16,777,216
#define NBINS_G   8192
#define NBINS_L   512
#define BIN_ELEMS 8192                    // floats per output bin region
#define NB        1024                    // binning blocks (64 per b)
#define K1T       1024
#define K3T       512
#define CH        4096                    // elems per K3 chunk
#define EPB       (N_ELEM / NB)           // 16384 elems per block
#define I4PB      (EPB / 4)               // 4096 int4 per block

// ---------------- K1: per-block 512-bin histogram ----------------
__global__ __launch_bounds__(K1T) void count_kernel(const int4* __restrict__ amx4,
                                                    int* __restrict__ hist) {
    __shared__ int h[NBINS_L];
    if (threadIdx.x < NBINS_L) h[threadIdx.x] = 0;
    __syncthreads();
    int base4 = blockIdx.x * I4PB;
    #pragma unroll
    for (int q = 0; q < I4PB / K1T; ++q) {       // 4
        int4 a = amx4[base4 + q * K1T + threadIdx.x];
        int y, x;
        y = (a.x >> 14) & 255; x = (a.x >> 6) & 255; atomicAdd(&h[(y << 1) | (x >> 7)], 1);
        y = (a.y >> 14) & 255; x = (a.y >> 6) & 255; atomicAdd(&h[(y << 1) | (x >> 7)], 1);
        y = (a.z >> 14) & 255; x = (a.z >> 6) & 255; atomicAdd(&h[(y << 1) | (x >> 7)], 1);
        y = (a.w >> 14) & 255; x = (a.w >> 6) & 255; atomicAdd(&h[(y << 1) | (x >> 7)], 1);
    }
    __syncthreads();
    if (threadIdx.x < NBINS_L)
        hist[blockIdx.x * NBINS_L + threadIdx.x] = h[threadIdx.x];
}

// ---------------- K2a: per-bin scan over the 64 blocks of its b ----------------
__global__ __launch_bounds__(256) void colscan_kernel(int* __restrict__ hist,
                                                      int* __restrict__ T) {
    int g = blockIdx.x * 256 + threadIdx.x;      // grid = NBINS_G/256 = 32
    int b = g >> 9, ybx = g & (NBINS_L - 1);
    int run = 0;
    const int BPB = NB / 16;                     // 64 blocks per b
    for (int j = 0; j < BPB; ++j) {
        int idx = (b * BPB + j) * NBINS_L + ybx;
        int v = hist[idx];
        hist[idx] = run;
        run += v;
    }
    T[g] = run;
}

// ---------------- K2b: exclusive scan of T[8192] -> G ----------------
__global__ __launch_bounds__(256) void scan_kernel(const int* __restrict__ T,
                                                   int* __restrict__ G) {
    __shared__ int part[256];
    const int PER = NBINS_G / 256;               // 32
    int t = threadIdx.x;
    int loc[PER];
    int s = 0;
    #pragma unroll
    for (int j = 0; j < PER; ++j) { loc[j] = s; s += T[t * PER + j]; }
    part[t] = s;
    __syncthreads();
    for (int off = 1; off < 256; off <<= 1) {
        int v = (t >= off) ? part[t - off] : 0;
        __syncthreads();
        part[t] += v;
        __syncthreads();
    }
    int pre = (t == 0) ? 0 : part[t - 1];
    #pragma unroll
    for (int j = 0; j < PER; ++j) G[t * PER + j] = pre + loc[j];
}

// ---------------- K3: chunked in-LDS counting sort -> bin-contiguous pair writes ----------------
__global__ __launch_bounds__(K3T) void scatter_kernel(const float4* __restrict__ upd4,
                                                      const int4* __restrict__ amx4,
                                                      const int* __restrict__ P,
                                                      const int* __restrict__ G,
                                                      int2* __restrict__ pairs) {
    __shared__ int cur[NBINS_L];      // running global cursor per local bin
    __shared__ int lstart[NBINS_L];   // chunk-local exclusive scan
    __shared__ int lcur[NBINS_L];     // histogram counter / placement cursor
    __shared__ int scratch[NBINS_L];
    __shared__ int2 staging[CH];      // 32 KiB

    int t = threadIdx.x;              // K3T == NBINS_L == 512, no guards needed
    int blk = blockIdx.x;
    int b = blk >> 6;                 // 64 blocks per b
    cur[t] = G[(b << 9) | t] + P[blk * NBINS_L + t];
    __syncthreads();

    int base4 = blk * I4PB;
    for (int ch = 0; ch < EPB / CH; ++ch) {      // 4 chunks
        int cb4 = base4 + ch * (CH / 4);
        int keys[8], vals[8];
        #pragma unroll
        for (int q = 0; q < 2; ++q) {
            int i = cb4 + q * K3T + t;           // coalesced
            int4   a = amx4[i];
            float4 u = upd4[i];
            int cc = (i << 2) & (C_ - 1);
            int y, x;
            y = (a.x >> 14) & 255; x = (a.x >> 6) & 255;
            keys[q * 4 + 0] = ((((y << 1) | (x >> 7))) << 13) | ((x & 127) << 6) | cc;
            vals[q * 4 + 0] = __float_as_int(u.x);
            y = (a.y >> 14) & 255; x = (a.y >> 6) & 255;
            keys[q * 4 + 1] = ((((y << 1) | (x >> 7))) << 13) | ((x & 127) << 6) | (cc + 1);
            vals[q * 4 + 1] = __float_as_int(u.y);
            y = (a.z >> 14) & 255; x = (a.z >> 6) & 255;
            keys[q * 4 + 2] = ((((y << 1) | (x >> 7))) << 13) | ((x & 127) << 6) | (cc + 2);
            vals[q * 4 + 2] = __float_as_int(u.z);
            y = (a.w >> 14) & 255; x = (a.w >> 6) & 255;
            keys[q * 4 + 3] = ((((y << 1) | (x >> 7))) << 13) | ((x & 127) << 6) | (cc + 3);
            vals[q * 4 + 3] = __float_as_int(u.w);
        }
        lcur[t] = 0;
        __syncthreads();
        #pragma unroll
        for (int j = 0; j < 8; ++j) atomicAdd(&lcur[keys[j] >> 13], 1);
        __syncthreads();
        // exclusive scan of lcur -> lstart
        scratch[t] = lcur[t];
        __syncthreads();
        for (int off = 1; off < NBINS_L; off <<= 1) {
            int v = (t >= off) ? scratch[t - off] : 0;
            __syncthreads();
            scratch[t] += v;
            __syncthreads();
        }
        int excl = (t == 0) ? 0 : scratch[t - 1];
        lstart[t] = excl;
        lcur[t] = excl;
        __syncthreads();
        // placement: LDS sort by bin
        #pragma unroll
        for (int j = 0; j < 8; ++j) {
            int slot = atomicAdd(&lcur[keys[j] >> 13], 1);
            staging[slot] = make_int2(keys[j], vals[j]);
        }
        __syncthreads();
        // copy-out: dense sorted order -> bin-contiguous global writes
        #pragma unroll
        for (int q = 0; q < CH / K3T; ++q) {     // 8
            int k = q * K3T + t;
            int2 s = staging[k];
            int bin = s.x >> 13;
            int dest = cur[bin] + (k - lstart[bin]);
            pairs[dest] = make_int2(s.x & 8191, s.y);
        }
        __syncthreads();
        cur[t] += lcur[t] - lstart[t];
        __syncthreads();
    }
}

// ---------------- K4: per-bin LDS accumulate + coalesced store ----------------
__global__ __launch_bounds__(512) void accum_kernel(const int2* __restrict__ pairs,
                                                    const int* __restrict__ T,
                                                    const int* __restrict__ G,
                                                    float4* __restrict__ out4) {
    __shared__ float acc[BIN_ELEMS];
    int bin = blockIdx.x;
    for (int j = threadIdx.x; j < BIN_ELEMS; j += 512) acc[j] = 0.f;
    __syncthreads();
    int n = T[bin], off = G[bin];
    for (int j = threadIdx.x; j < n; j += 512) {
        int2 p = pairs[off + j];
        atomicAdd(&acc[p.x], __int_as_float(p.y));
    }
    __syncthreads();
    float4* dst = out4 + (size_t)bin * (BIN_ELEMS / 4);
    for (int j = threadIdx.x; j < BIN_ELEMS / 4; j += 512) {
        dst[j] = make_float4(acc[4 * j], acc[4 * j + 1], acc[4 * j + 2], acc[4 * j + 3]);
    }
}

// ---------------- Fallback (atomic path) ----------------
__global__ void zero_out_kernel(float4* __restrict__ out, int n4) {
    int stride = gridDim.x * blockDim.x;
    for (int i = blockIdx.x * blockDim.x + threadIdx.x; i < n4; i += stride)
        out[i] = make_float4(0.f, 0.f, 0.f, 0.f);
}

__global__ void unpool_atomic_kernel(const float4* __restrict__ upd4,
                                     const int4* __restrict__ amx4,
                                     float* __restrict__ out, int n4) {
    int i = blockIdx.x * blockDim.x + threadIdx.x;
    if (i >= n4) return;
    float4 u = upd4[i];
    int4   a = amx4[i];
    int e = i << 2;
    int c = e & (C_ - 1);
    int base_b = (e >> 20) << 22;
    int y, x;
    y = (a.x >> 14) & 255; x = (a.x >> 6) & 255;
    atomicAdd(&out[base_b + (y << 14) + (x << 6) + c], u.x);
    y = (a.y >> 14) & 255; x = (a.y >> 6) & 255;
    atomicAdd(&out[base_b + (y << 14) + (x << 6) + c + 1], u.y);
    y = (a.z >> 14) & 255; x = (a.z >> 6) & 255;
    atomicAdd(&out[base_b + (y << 14) + (x << 6) + c + 2], u.z);
    y = (a.w >> 14) & 255; x = (a.w >> 6) & 255;
    atomicAdd(&out[base_b + (y << 14) + (x << 6) + c + 3], u.w);
}

extern "C" void kernel_launch(void* const* d_in, const int* in_sizes, int n_in,
                              void* d_out, int out_size, void* d_ws, size_t ws_size,
                              hipStream_t stream) {
    const float* updates = (const float*)d_in[0];
    const int*   argmax  = (const int*)d_in[1];

    size_t pairs_bytes = (size_t)N_ELEM * 8;
    size_t hist_bytes  = (size_t)NB * NBINS_L * 4;
    size_t need = pairs_bytes + hist_bytes + 2 * (size_t)NBINS_G * 4;

    if (in_sizes[0] == N_ELEM && ws_size >= need) {
        char* ws = (char*)d_ws;
        int2* pairs = (int2*)ws;
        int*  hist  = (int*)(ws + pairs_bytes);
        int*  T     = (int*)(ws + pairs_bytes + hist_bytes);
        int*  G     = T + NBINS_G;

        count_kernel  <<<NB, K1T, 0, stream>>>((const int4*)argmax, hist);
        colscan_kernel<<<NBINS_G / 256, 256, 0, stream>>>(hist, T);
        scan_kernel   <<<1, 256, 0, stream>>>(T, G);
        scatter_kernel<<<NB, K3T, 0, stream>>>((const float4*)updates,
                                               (const int4*)argmax, hist, G, pairs);
        accum_kernel  <<<NBINS_G, 512, 0, stream>>>(pairs, T, G, (float4*)d_out);
    } else {
        int n_out4 = out_size >> 2;
        zero_out_kernel<<<2048, 256, 0, stream>>>((float4*)d_out, n_out4);
        int n4 = in_sizes[0] >> 2;
        unpool_atomic_kernel<<<(n4 + 255) / 256, 256, 0, stream>>>(
            (const float4*)updates, (const int4*)argmax, (float*)d_out, n4);
    }
}